// Round 1
// baseline (1039.419 us; speedup 1.0000x reference)
//
#include <hip/hip_runtime.h>
#include <math.h>

typedef __bf16 v8bf __attribute__((ext_vector_type(8)));
typedef float  v4f  __attribute__((ext_vector_type(4)));

#define EPS_BN 1e-5f
#define Q_TOTAL 16384
#define N_MEM   262144
#define D_DIM   64
#define SLICES  32
#define SLICE_LEN (N_MEM / SLICES)   /* 8192 */
#define CHUNK   32
#define NCHUNKS (SLICE_LEN / CHUNK)  /* 256 */

// ---------------------------------------------------------------------------
// async global->LDS helper (width 16B). LDS dest is wave-uniform base +
// lane*16 (HW semantics), so the bank-swizzle must be applied to the GLOBAL
// source addresses, not the LDS layout.
__device__ __forceinline__ void gload_lds16(const void* g, void* l) {
    __builtin_amdgcn_global_load_lds(
        (const __attribute__((address_space(1))) void*)g,
        (__attribute__((address_space(3))) void*)l, 16, 0, 0);
}

// ---------------------------------------------------------------------------
// conv0: [256,1,64,64] -> [256,16,32,32], 3x3 s2 p1 + BN + ReLU
__global__ void conv0_kernel(const float* __restrict__ x,
                             const float* __restrict__ w, const float* __restrict__ bias,
                             const float* __restrict__ gamma, const float* __restrict__ beta,
                             const float* __restrict__ mean, const float* __restrict__ var,
                             float* __restrict__ out) {
    int idx = blockIdx.x * 256 + threadIdx.x;      // b*16384 + c*1024 + y*32 + x
    int xo = idx & 31, yo = (idx >> 5) & 31, c = (idx >> 10) & 15, b = idx >> 14;
    const float* xp = x + (size_t)b * 4096;
    const float* wc = w + c * 9;
    float acc = 0.f;
#pragma unroll
    for (int dy = 0; dy < 3; ++dy) {
        int iy = 2 * yo + dy - 1;
        if (iy < 0 || iy > 63) continue;
#pragma unroll
        for (int dx = 0; dx < 3; ++dx) {
            int ix = 2 * xo + dx - 1;
            if (ix < 0 || ix > 63) continue;
            acc += wc[dy * 3 + dx] * xp[iy * 64 + ix];
        }
    }
    acc += bias[c];
    float sc = gamma[c] * rsqrtf(var[c] + EPS_BN);
    float v  = (acc - mean[c]) * sc + beta[c];
    out[idx] = fmaxf(v, 0.f);
}

// conv1: [256,16,32,32] -> [256,32,16,16]
__global__ void conv1_kernel(const float* __restrict__ in,
                             const float* __restrict__ w, const float* __restrict__ bias,
                             const float* __restrict__ gamma, const float* __restrict__ beta,
                             const float* __restrict__ mean, const float* __restrict__ var,
                             float* __restrict__ out) {
    int t = threadIdx.x;                           // block covers one (b,c): 16x16 px
    int xo = t & 15, yo = (t >> 4) & 15;
    int c = blockIdx.x & 31, b = blockIdx.x >> 5;  // grid 256*32
    const float* ip = in + (size_t)b * 16384;
    const float* wp = w + c * 144;
    float acc = 0.f;
    for (int ci = 0; ci < 16; ++ci) {
        const float* pl = ip + ci * 1024;
        const float* wc = wp + ci * 9;
#pragma unroll
        for (int dy = 0; dy < 3; ++dy) {
            int iy = 2 * yo + dy - 1;
            if (iy < 0 || iy > 31) continue;
#pragma unroll
            for (int dx = 0; dx < 3; ++dx) {
                int ix = 2 * xo + dx - 1;
                if (ix < 0 || ix > 31) continue;
                acc += wc[dy * 3 + dx] * pl[iy * 32 + ix];
            }
        }
    }
    acc += bias[c];
    float sc = gamma[c] * rsqrtf(var[c] + EPS_BN);
    float v  = (acc - mean[c]) * sc + beta[c];
    out[((size_t)(b * 32 + c) * 16 + yo) * 16 + xo] = fmaxf(v, 0.f);
}

// conv2: [256,32,16,16] -> [256,64,8,8]
__global__ void conv2_kernel(const float* __restrict__ in,
                             const float* __restrict__ w, const float* __restrict__ bias,
                             const float* __restrict__ gamma, const float* __restrict__ beta,
                             const float* __restrict__ mean, const float* __restrict__ var,
                             float* __restrict__ out) {
    int t = threadIdx.x;                          // 4 channels x 64 px per block
    int xo = t & 7, yo = (t >> 3) & 7;
    int b = blockIdx.x >> 4, cg = blockIdx.x & 15; // grid 256*16
    int c = cg * 4 + (t >> 6);
    const float* ip = in + (size_t)b * 8192;
    const float* wp = w + c * 288;
    float acc = 0.f;
    for (int ci = 0; ci < 32; ++ci) {
        const float* pl = ip + ci * 256;
        const float* wc = wp + ci * 9;
#pragma unroll
        for (int dy = 0; dy < 3; ++dy) {
            int iy = 2 * yo + dy - 1;
            if (iy < 0 || iy > 15) continue;
#pragma unroll
            for (int dx = 0; dx < 3; ++dx) {
                int ix = 2 * xo + dx - 1;
                if (ix < 0 || ix > 15) continue;
                acc += wc[dy * 3 + dx] * pl[iy * 16 + ix];
            }
        }
    }
    acc += bias[c];
    float sc = gamma[c] * rsqrtf(var[c] + EPS_BN);
    float v  = (acc - mean[c]) * sc + beta[c];
    out[((size_t)(b * 64 + c) * 8 + yo) * 8 + xo] = fmaxf(v, 0.f);
}

// ---------------------------------------------------------------------------
// qnorm: y2 [256,64,8,8] -> transpose per batch -> L2 normalize -> bf16 pack
// q[(b*64+p)*64 + d], qsq computed from the bf16-rounded values.
__global__ void qnorm_kernel(const float* __restrict__ y2,
                             __bf16* __restrict__ q, float* __restrict__ qsq) {
    __shared__ float  L1s[4096];
    __shared__ __bf16 L2s[4096];
    int b = blockIdx.x, t = threadIdx.x;          // 64 threads
    const float* src = y2 + (size_t)b * 4096;
    for (int i = t; i < 4096; i += 64) L1s[i] = src[i];
    __syncthreads();
    int p = t;
    float ss = 0.f;
    for (int d = 0; d < 64; ++d) { float v = L1s[d * 64 + p]; ss += v * v; }
    float inv = 1.f / fmaxf(sqrtf(ss), 1e-12f);
    float q2 = 0.f;
    for (int d = 0; d < 64; ++d) {
        float v = L1s[d * 64 + p] * inv;
        __bf16 bv = (__bf16)v;
        L2s[p * 64 + d] = bv;
        float fb = (float)bv;
        q2 += fb * fb;
    }
    qsq[b * 64 + p] = q2;
    __syncthreads();
    for (int p2 = 0; p2 < 64; ++p2)
        q[((size_t)(b * 64 + p2)) * 64 + t] = L2s[p2 * 64 + t];
}

// mbnorm: normalize bank rows, pack bf16, msq from bf16-rounded values.
__global__ void mbnorm_kernel(const float* __restrict__ mb,
                              __bf16* __restrict__ mbbf, float* __restrict__ msq) {
    int row  = blockIdx.x * 4 + (threadIdx.x >> 6);
    int lane = threadIdx.x & 63;
    float v = mb[(size_t)row * 64 + lane];
    float ss = v * v;
#pragma unroll
    for (int o = 1; o < 64; o <<= 1) ss += __shfl_xor(ss, o, 64);
    float inv = 1.f / fmaxf(sqrtf(ss), 1e-12f);
    __bf16 bv = (__bf16)(v * inv);
    mbbf[(size_t)row * 64 + lane] = bv;
    float fb = (float)bv;
    float s2 = fb * fb;
#pragma unroll
    for (int o = 1; o < 64; o <<= 1) s2 += __shfl_xor(s2, o, 64);
    if (lane == 0) msq[row] = s2;
}

__global__ void initmin_kernel(unsigned int* __restrict__ mind2) {
    int i = blockIdx.x * 256 + threadIdx.x;
    if (i < Q_TOTAL) mind2[i] = 0x7f800000u; // +inf
}

// ---------------------------------------------------------------------------
// Distance kernel: min_n ||q_m - mb_n||^2 via MFMA bf16.
// Block = 256 thr (4 waves). BM=256 (wave: 4 strips of 16 rows, A frags in
// registers for the whole kernel). Bank streamed in 32-row chunks via
// global_load_lds(16B) with XOR(col^row&7) swizzle folded into the global
// fetch address. Per chunk/wave: 4 ds_read_b128 + 16 MFMA 16x16x32_bf16.
// Track min(msq - 2*dot) per row; add qsq at the end; atomicMin (uint pun).
__global__ void dist_kernel(const __bf16* __restrict__ q, const float* __restrict__ qsq,
                            const __bf16* __restrict__ mb, const float* __restrict__ msq,
                            unsigned int* __restrict__ mind2) {
    __shared__ __align__(16) __bf16 Bs[CHUNK * 64];   // 4 KB
    const int t    = threadIdx.x;
    const int wave = t >> 6;
    const int lane = t & 63;
    const int col  = lane & 15;   // n-within-tile (B) / m-row selector (A)
    const int quad = lane >> 4;   // 0..3
    const int mtile = blockIdx.x; // 64 tiles of 256 query rows
    const int slice = blockIdx.y; // SLICES slices over the bank
    const int mbase = mtile * 256 + wave * 64;

    // A fragments: 4 strips x 2 k-steps, register resident.
    v8bf a[4][2];
#pragma unroll
    for (int s = 0; s < 4; ++s) {
        const __bf16* ap = q + (size_t)(mbase + s * 16 + col) * 64;
        a[s][0] = *(const v8bf*)(ap + quad * 8);
        a[s][1] = *(const v8bf*)(ap + 32 + quad * 8);
    }
    v4f qs[4];
#pragma unroll
    for (int s = 0; s < 4; ++s)
        qs[s] = *(const v4f*)(qsq + mbase + s * 16 + quad * 4);

    float tmin[4][4];
#pragma unroll
    for (int s = 0; s < 4; ++s)
#pragma unroll
        for (int r = 0; r < 4; ++r) tmin[s][r] = 3.0e38f;

    // staging source address (swizzled): thread t owns LDS 16B-granule t.
    const int rg  = t >> 3;                 // chunk row 0..31
    const int cg8 = (t & 7) ^ (rg & 7);     // swizzled 16B column
    const __bf16* gp = mb + (size_t)(slice * SLICE_LEN) * 64 + rg * 64 + cg8 * 8;
    char* ldst = (char*)Bs + wave * 1024;
    const char* bsp = (const char*)Bs;

    // frag ds_read offsets (undo the swizzle)
    const int row0 = col,      row1 = 16 + col;
    const int c00 = quad,      c01 = 4 + quad;
    const int off00 = row0 * 128 + ((c00 ^ (row0 & 7)) << 4);
    const int off01 = row0 * 128 + ((c01 ^ (row0 & 7)) << 4);
    const int off10 = row1 * 128 + ((c00 ^ (row1 & 7)) << 4);
    const int off11 = row1 * 128 + ((c01 ^ (row1 & 7)) << 4);

    int nb = slice * SLICE_LEN;
    for (int ch = 0; ch < NCHUNKS; ++ch) {
        gload_lds16(gp, ldst);
        __syncthreads();                      // drains vmcnt before barrier
        float ms0 = msq[nb + col];
        float ms1 = msq[nb + 16 + col];
        v8bf b00 = *(const v8bf*)(bsp + off00);
        v8bf b01 = *(const v8bf*)(bsp + off01);
        v8bf b10 = *(const v8bf*)(bsp + off10);
        v8bf b11 = *(const v8bf*)(bsp + off11);
#pragma unroll
        for (int s = 0; s < 4; ++s) {
            v4f acc0 = {0.f, 0.f, 0.f, 0.f};
            acc0 = __builtin_amdgcn_mfma_f32_16x16x32_bf16(a[s][0], b00, acc0, 0, 0, 0);
            acc0 = __builtin_amdgcn_mfma_f32_16x16x32_bf16(a[s][1], b01, acc0, 0, 0, 0);
            v4f acc1 = {0.f, 0.f, 0.f, 0.f};
            acc1 = __builtin_amdgcn_mfma_f32_16x16x32_bf16(a[s][0], b10, acc1, 0, 0, 0);
            acc1 = __builtin_amdgcn_mfma_f32_16x16x32_bf16(a[s][1], b11, acc1, 0, 0, 0);
#pragma unroll
            for (int r = 0; r < 4; ++r) {
                float c0 = fmaf(-2.f, acc0[r], ms0);
                float c1 = fmaf(-2.f, acc1[r], ms1);
                tmin[s][r] = fminf(tmin[s][r], fminf(c0, c1));
            }
        }
        __syncthreads();                      // LDS reuse next chunk
        gp += CHUNK * 64;
        nb += CHUNK;
    }

    // cross-lane min over the 16 columns of each quad group
#pragma unroll
    for (int s = 0; s < 4; ++s)
#pragma unroll
        for (int r = 0; r < 4; ++r) {
            float v = tmin[s][r];
            v = fminf(v, __shfl_xor(v, 1, 64));
            v = fminf(v, __shfl_xor(v, 2, 64));
            v = fminf(v, __shfl_xor(v, 4, 64));
            v = fminf(v, __shfl_xor(v, 8, 64));
            tmin[s][r] = v;
        }
    if (col == 0) {
#pragma unroll
        for (int s = 0; s < 4; ++s)
#pragma unroll
            for (int r = 0; r < 4; ++r) {
                int m = mbase + s * 16 + quad * 4 + r;   // C/D row = quad*4+reg
                float d2 = fmaxf(qs[s][r] + tmin[s][r], 0.f);
                atomicMin(mind2 + m, __float_as_uint(d2));
            }
    }
}

// finalize: out[b] = max_p sqrt(mind2[b*64+p])
__global__ void finalize_kernel(const unsigned int* __restrict__ mind2,
                                float* __restrict__ out) {
    int b = blockIdx.x, l = threadIdx.x;
    float v = __uint_as_float(mind2[b * 64 + l]);
    float d = sqrtf(fmaxf(v, 0.f));
#pragma unroll
    for (int o = 1; o < 64; o <<= 1) d = fmaxf(d, __shfl_xor(d, o, 64));
    if (l == 0) out[b] = d;
}

// ---------------------------------------------------------------------------
extern "C" void kernel_launch(void* const* d_in, const int* in_sizes, int n_in,
                              void* d_out, int out_size, void* d_ws, size_t ws_size,
                              hipStream_t stream) {
    (void)in_sizes; (void)n_in; (void)out_size; (void)ws_size;
    const float* x     = (const float*)d_in[0];
    const float* mbank = (const float*)d_in[1];
    const float* w0 = (const float*)d_in[2],  *b0 = (const float*)d_in[3];
    const float* g0 = (const float*)d_in[4],  *be0 = (const float*)d_in[5];
    const float* mn0 = (const float*)d_in[6], *vr0 = (const float*)d_in[7];
    const float* w1 = (const float*)d_in[8],  *b1 = (const float*)d_in[9];
    const float* g1 = (const float*)d_in[10], *be1 = (const float*)d_in[11];
    const float* mn1 = (const float*)d_in[12], *vr1 = (const float*)d_in[13];
    const float* w2 = (const float*)d_in[14], *b2 = (const float*)d_in[15];
    const float* g2 = (const float*)d_in[16], *be2 = (const float*)d_in[17];
    const float* mn2 = (const float*)d_in[18], *vr2 = (const float*)d_in[19];

    char* ws = (char*)d_ws;
    float*        y0    = (float*)(ws + 0);              // 16.78 MB
    float*        y1    = (float*)(ws + 16777216);       // 8.39 MB
    float*        y2    = (float*)(ws + 25165824);       // 4.19 MB
    __bf16*       qbf   = (__bf16*)(ws + 29360128);      // 2.10 MB
    float*        qsq   = (float*)(ws + 31457280);       // 64 KB
    __bf16*       mbbf  = (__bf16*)(ws + 31522816);      // 33.55 MB
    float*        msq   = (float*)(ws + 65077248);       // 1.05 MB
    unsigned int* mind2 = (unsigned int*)(ws + 66125824);// 64 KB

    conv0_kernel<<<16384, 256, 0, stream>>>(x, w0, b0, g0, be0, mn0, vr0, y0);
    conv1_kernel<<<8192, 256, 0, stream>>>(y0, w1, b1, g1, be1, mn1, vr1, y1);
    conv2_kernel<<<4096, 256, 0, stream>>>(y1, w2, b2, g2, be2, mn2, vr2, y2);
    qnorm_kernel<<<256, 64, 0, stream>>>(y2, qbf, qsq);
    mbnorm_kernel<<<65536, 256, 0, stream>>>(mbank, mbbf, msq);
    initmin_kernel<<<64, 256, 0, stream>>>(mind2);
    dist_kernel<<<dim3(64, SLICES), 256, 0, stream>>>(qbf, qsq, mbbf, msq, mind2);
    finalize_kernel<<<256, 64, 0, stream>>>(mind2, (float*)d_out);
}

// Round 2
// 751.958 us; speedup vs baseline: 1.3823x; 1.3823x over previous
//
#include <hip/hip_runtime.h>
#include <math.h>

typedef __bf16 v8bf __attribute__((ext_vector_type(8)));
typedef float  v16f __attribute__((ext_vector_type(16)));

#define EPS_BN 1e-5f
#define Q_TOTAL 16384
#define N_MEM   262144
#define SLICES  32
#define SLICE_LEN (N_MEM / SLICES)   /* 8192 */
#define CHUNK   128
#define NCHUNKS (SLICE_LEN / CHUNK)  /* 64 */

// async global->LDS, 16B/lane. LDS dest is wave-uniform base + lane*16, so
// the bank swizzle must be folded into the GLOBAL source addresses.
__device__ __forceinline__ void gload_lds16(const void* g, void* l) {
    __builtin_amdgcn_global_load_lds(
        (const __attribute__((address_space(1))) void*)g,
        (__attribute__((address_space(3))) void*)l, 16, 0, 0);
}

// ---------------------------------------------------------------------------
// conv0: [256,1,64,64] -> [256,16,32,32], 3x3 s2 p1 + BN + ReLU (unchanged)
__global__ void conv0_kernel(const float* __restrict__ x,
                             const float* __restrict__ w, const float* __restrict__ bias,
                             const float* __restrict__ gamma, const float* __restrict__ beta,
                             const float* __restrict__ mean, const float* __restrict__ var,
                             float* __restrict__ out) {
    int idx = blockIdx.x * 256 + threadIdx.x;
    int xo = idx & 31, yo = (idx >> 5) & 31, c = (idx >> 10) & 15, b = idx >> 14;
    const float* xp = x + (size_t)b * 4096;
    const float* wc = w + c * 9;
    float acc = 0.f;
#pragma unroll
    for (int dy = 0; dy < 3; ++dy) {
        int iy = 2 * yo + dy - 1;
        if (iy < 0) continue;                  // iy <= 63 always
#pragma unroll
        for (int dx = 0; dx < 3; ++dx) {
            int ix = 2 * xo + dx - 1;
            if (ix < 0) continue;
            acc += wc[dy * 3 + dx] * xp[iy * 64 + ix];
        }
    }
    acc += bias[c];
    float sc = gamma[c] * rsqrtf(var[c] + EPS_BN);
    float v  = (acc - mean[c]) * sc + beta[c];
    out[idx] = fmaxf(v, 0.f);
}

// ---------------------------------------------------------------------------
// conv1: [256,16,32,32] -> [256,32,16,16]. LDS-staged: block = (image, 8-ch
// group). Input 64KB + weights 4.6KB in LDS, BN folded, thread = 1 pixel x 8c.
__global__ void conv1_kernel(const float* __restrict__ in,
                             const float* __restrict__ w, const float* __restrict__ bias,
                             const float* __restrict__ gamma, const float* __restrict__ beta,
                             const float* __restrict__ mean, const float* __restrict__ var,
                             float* __restrict__ out) {
    __shared__ float in_s[16384];
    __shared__ float w_s[1152];
    __shared__ float sc_s[8], sh_s[8];
    int b = blockIdx.x >> 2, cg = blockIdx.x & 3;
    int t = threadIdx.x;
    const float4* ip4 = (const float4*)(in + (size_t)b * 16384);
    float4* is4 = (float4*)in_s;
    for (int i = t; i < 4096; i += 256) is4[i] = ip4[i];
    for (int i = t; i < 1152; i += 256) w_s[i] = w[cg * 1152 + i];
    if (t < 8) {
        int c = cg * 8 + t;
        float sc = gamma[c] * rsqrtf(var[c] + EPS_BN);
        sc_s[t] = sc;
        sh_s[t] = (bias[c] - mean[c]) * sc + beta[c];
    }
    __syncthreads();
    int xo = t & 15, yo = t >> 4;
    float acc[8];
#pragma unroll
    for (int c = 0; c < 8; ++c) acc[c] = 0.f;
    int iy0 = 2 * yo - 1, ix0 = 2 * xo - 1;
    for (int ci = 0; ci < 16; ++ci) {
        const float* base = in_s + ci * 1024;
        float r[9];
#pragma unroll
        for (int dy = 0; dy < 3; ++dy) {
            int iy = iy0 + dy;
            int iyc = iy < 0 ? 0 : iy;
#pragma unroll
            for (int dx = 0; dx < 3; ++dx) {
                int ix = ix0 + dx;
                int ixc = ix < 0 ? 0 : ix;
                float v = base[iyc * 32 + ixc];
                r[dy * 3 + dx] = (iy >= 0 && ix >= 0) ? v : 0.f;
            }
        }
#pragma unroll
        for (int c = 0; c < 8; ++c) {
            const float* wp = w_s + (c * 16 + ci) * 9;
#pragma unroll
            for (int k = 0; k < 9; ++k) acc[c] = fmaf(wp[k], r[k], acc[c]);
        }
    }
#pragma unroll
    for (int c = 0; c < 8; ++c) {
        float v = fmaf(acc[c], sc_s[c], sh_s[c]);
        out[((size_t)(b * 32 + cg * 8 + c) * 16 + yo) * 16 + xo] = fmaxf(v, 0.f);
    }
}

// ---------------------------------------------------------------------------
// conv2: [256,32,16,16] -> [256,64,8,8]. Same scheme: block = (image, 16-ch
// group); thread = 1 pixel x 4 channels.
__global__ void conv2_kernel(const float* __restrict__ in,
                             const float* __restrict__ w, const float* __restrict__ bias,
                             const float* __restrict__ gamma, const float* __restrict__ beta,
                             const float* __restrict__ mean, const float* __restrict__ var,
                             float* __restrict__ out) {
    __shared__ float in_s[8192];
    __shared__ float w_s[4608];
    __shared__ float sc_s[16], sh_s[16];
    int b = blockIdx.x >> 2, cg = blockIdx.x & 3;
    int t = threadIdx.x;
    const float4* ip4 = (const float4*)(in + (size_t)b * 8192);
    float4* is4 = (float4*)in_s;
    for (int i = t; i < 2048; i += 256) is4[i] = ip4[i];
    for (int i = t; i < 4608; i += 256) w_s[i] = w[cg * 4608 + i];
    if (t < 16) {
        int c = cg * 16 + t;
        float sc = gamma[c] * rsqrtf(var[c] + EPS_BN);
        sc_s[t] = sc;
        sh_s[t] = (bias[c] - mean[c]) * sc + beta[c];
    }
    __syncthreads();
    int xo = t & 7, yo = (t >> 3) & 7, cs = t >> 6;   // cs: which 4-ch subgroup
    float acc[4];
#pragma unroll
    for (int l = 0; l < 4; ++l) acc[l] = 0.f;
    int iy0 = 2 * yo - 1, ix0 = 2 * xo - 1;
    for (int ci = 0; ci < 32; ++ci) {
        const float* base = in_s + ci * 256;
        float r[9];
#pragma unroll
        for (int dy = 0; dy < 3; ++dy) {
            int iy = iy0 + dy;
            int iyc = iy < 0 ? 0 : iy;
#pragma unroll
            for (int dx = 0; dx < 3; ++dx) {
                int ix = ix0 + dx;
                int ixc = ix < 0 ? 0 : ix;
                float v = base[iyc * 16 + ixc];
                r[dy * 3 + dx] = (iy >= 0 && ix >= 0) ? v : 0.f;
            }
        }
#pragma unroll
        for (int l = 0; l < 4; ++l) {
            const float* wp = w_s + ((cs * 4 + l) * 32 + ci) * 9;
#pragma unroll
            for (int k = 0; k < 9; ++k) acc[l] = fmaf(wp[k], r[k], acc[l]);
        }
    }
#pragma unroll
    for (int l = 0; l < 4; ++l) {
        int c = cg * 16 + cs * 4 + l;
        float v = fmaf(acc[l], sc_s[cs * 4 + l], sh_s[cs * 4 + l]);
        out[((size_t)(b * 64 + c) * 8 + yo) * 8 + xo] = fmaxf(v, 0.f);
    }
}

// ---------------------------------------------------------------------------
// qnorm: y2 [256,64,8,8] -> transpose -> L2 normalize -> bf16; qsq from the
// bf16-rounded values (keeps d^2 self-consistent).
__global__ void qnorm_kernel(const float* __restrict__ y2,
                             __bf16* __restrict__ q, float* __restrict__ qsq) {
    __shared__ float  L1s[4096];
    __shared__ __bf16 L2s[4096];
    int b = blockIdx.x, t = threadIdx.x;          // 64 threads
    const float* src = y2 + (size_t)b * 4096;
    for (int i = t; i < 4096; i += 64) L1s[i] = src[i];
    __syncthreads();
    int p = t;
    float ss = 0.f;
    for (int d = 0; d < 64; ++d) { float v = L1s[d * 64 + p]; ss += v * v; }
    float inv = 1.f / fmaxf(sqrtf(ss), 1e-12f);
    float q2 = 0.f;
    for (int d = 0; d < 64; ++d) {
        float v = L1s[d * 64 + p] * inv;
        __bf16 bv = (__bf16)v;
        L2s[p * 64 + d] = bv;
        float fb = (float)bv;
        q2 += fb * fb;
    }
    qsq[b * 64 + p] = q2;
    __syncthreads();
    for (int p2 = 0; p2 < 64; ++p2)
        q[((size_t)(b * 64 + p2)) * 64 + t] = L2s[p2 * 64 + t];
}

// mbnorm: normalize bank rows, pack bf16, msq from bf16-rounded values.
__global__ void mbnorm_kernel(const float* __restrict__ mb,
                              __bf16* __restrict__ mbbf, float* __restrict__ msq) {
    int row  = blockIdx.x * 4 + (threadIdx.x >> 6);
    int lane = threadIdx.x & 63;
    float v = mb[(size_t)row * 64 + lane];
    float ss = v * v;
#pragma unroll
    for (int o = 1; o < 64; o <<= 1) ss += __shfl_xor(ss, o, 64);
    float inv = 1.f / fmaxf(sqrtf(ss), 1e-12f);
    __bf16 bv = (__bf16)(v * inv);
    mbbf[(size_t)row * 64 + lane] = bv;
    float fb = (float)bv;
    float s2 = fb * fb;
#pragma unroll
    for (int o = 1; o < 64; o <<= 1) s2 += __shfl_xor(s2, o, 64);
    if (lane == 0) msq[row] = s2;
}

__global__ void initmin_kernel(unsigned int* __restrict__ mind2) {
    int i = blockIdx.x * 256 + threadIdx.x;
    if (i < Q_TOTAL) mind2[i] = 0x7f800000u; // +inf
}

// ---------------------------------------------------------------------------
// dist v2: 32x32x16 bf16 MFMA, msq folded into the C-operand init
// (acc = dot - msq/2), epilogue = single fmax per element. CHUNK=128 rows,
// double-buffered LDS, ONE barrier per chunk (prefetch issued post-barrier).
// A (2 strips x 4 ksteps) register-resident; layouts: A m=lane&31,
// k=(lane>>5)*8+j; B n=lane&31, same k; C/D col=lane&31,
// row=(r&3)+8*(r>>2)+4*(lane>>5).
__global__ __launch_bounds__(256, 2)
void dist_kernel(const __bf16* __restrict__ q, const float* __restrict__ qsq,
                 const __bf16* __restrict__ mb, const float* __restrict__ msq,
                 unsigned int* __restrict__ mind2) {
    __shared__ __align__(16) __bf16 Bs[2][CHUNK * 64];   // 2 x 16 KB
    const int t = threadIdx.x;
    const int wave = t >> 6, lane = t & 63;
    const int n32 = lane & 31, half = lane >> 5;
    const int mbase = blockIdx.x * 256 + wave * 64;
    const int slice = blockIdx.y;

    v8bf a[2][4];
#pragma unroll
    for (int s = 0; s < 2; ++s)
#pragma unroll
        for (int ks = 0; ks < 4; ++ks)
            a[s][ks] = *(const v8bf*)(q + (size_t)(mbase + s * 32 + n32) * 64
                                        + ks * 16 + half * 8);

    float tmax[2][16];
#pragma unroll
    for (int s = 0; s < 2; ++s)
#pragma unroll
        for (int r = 0; r < 16; ++r) tmax[s][r] = -3.0e38f;

    // staging: 4 granule-sets of 256 x 16B per chunk; XOR(col^row&7) swizzle
    // folded into the global source address.
    const __bf16* gbase = mb + (size_t)slice * SLICE_LEN * 64;
    const __bf16* src0; const __bf16* src1; const __bf16* src2; const __bf16* src3;
    int d0, d1, d2o, d3;
    {
        int g0 = t,        r0 = g0 >> 3, c0 = (g0 & 7) ^ (r0 & 7);
        int g1 = t + 256,  r1 = g1 >> 3, c1 = (g1 & 7) ^ (r1 & 7);
        int g2 = t + 512,  r2 = g2 >> 3, c2 = (g2 & 7) ^ (r2 & 7);
        int g3 = t + 768,  r3 = g3 >> 3, c3 = (g3 & 7) ^ (r3 & 7);
        src0 = gbase + r0 * 64 + c0 * 8;  d0  = wave * 1024;
        src1 = gbase + r1 * 64 + c1 * 8;  d1  = 4096 + wave * 1024;
        src2 = gbase + r2 * 64 + c2 * 8;  d2o = 8192 + wave * 1024;
        src3 = gbase + r3 * 64 + c3 * 8;  d3  = 12288 + wave * 1024;
    }
    // prologue: chunk 0 -> buf 0
    gload_lds16(src0, (char*)Bs[0] + d0);  src0 += CHUNK * 64;
    gload_lds16(src1, (char*)Bs[0] + d1);  src1 += CHUNK * 64;
    gload_lds16(src2, (char*)Bs[0] + d2o); src2 += CHUNK * 64;
    gload_lds16(src3, (char*)Bs[0] + d3);  src3 += CHUNK * 64;

    const float* msbase = msq + slice * SLICE_LEN + n32;

    auto step = [&](const char* bp, char* pdst, bool pref, int nbofs) {
        __syncthreads();          // drains this thread's staging (vmcnt0) + sync
        if (pref) {
            gload_lds16(src0, pdst + d0);  src0 += CHUNK * 64;
            gload_lds16(src1, pdst + d1);  src1 += CHUNK * 64;
            gload_lds16(src2, pdst + d2o); src2 += CHUNK * 64;
            gload_lds16(src3, pdst + d3);  src3 += CHUNK * 64;
        }
#pragma unroll
        for (int nt = 0; nt < 4; ++nt) {
            float ms = msbase[nbofs + nt * 32];
            float cinit = -0.5f * ms;
            v16f C;
#pragma unroll
            for (int r = 0; r < 16; ++r) C[r] = cinit;
            const int n = nt * 32 + n32;
            const int rowb = n * 128;
            const int sw = (n & 7) << 4;
            v8bf bf[4];
#pragma unroll
            for (int ks = 0; ks < 4; ++ks)
                bf[ks] = *(const v8bf*)(bp + rowb + (((ks * 2 + half) << 4) ^ sw));
            v16f a0 = __builtin_amdgcn_mfma_f32_32x32x16_bf16(a[0][0], bf[0], C, 0, 0, 0);
            v16f a1 = __builtin_amdgcn_mfma_f32_32x32x16_bf16(a[1][0], bf[0], C, 0, 0, 0);
#pragma unroll
            for (int ks = 1; ks < 4; ++ks) {
                a0 = __builtin_amdgcn_mfma_f32_32x32x16_bf16(a[0][ks], bf[ks], a0, 0, 0, 0);
                a1 = __builtin_amdgcn_mfma_f32_32x32x16_bf16(a[1][ks], bf[ks], a1, 0, 0, 0);
            }
#pragma unroll
            for (int r = 0; r < 16; ++r) {
                tmax[0][r] = fmaxf(tmax[0][r], a0[r]);
                tmax[1][r] = fmaxf(tmax[1][r], a1[r]);
            }
        }
    };

    for (int ch = 0; ch < NCHUNKS; ch += 2) {
        step((const char*)Bs[0], (char*)Bs[1], true, ch * CHUNK);
        step((const char*)Bs[1], (char*)Bs[0], ch + 2 < NCHUNKS, (ch + 1) * CHUNK);
    }

    // min_n(msq - 2 dot) = -2 * max_n(dot - msq/2) = -2 * tmax
#pragma unroll
    for (int s = 0; s < 2; ++s)
#pragma unroll
        for (int r = 0; r < 16; ++r) {
            float v = tmax[s][r];
            v = fmaxf(v, __shfl_xor(v, 1, 64));
            v = fmaxf(v, __shfl_xor(v, 2, 64));
            v = fmaxf(v, __shfl_xor(v, 4, 64));
            v = fmaxf(v, __shfl_xor(v, 8, 64));
            v = fmaxf(v, __shfl_xor(v, 16, 64));
            tmax[s][r] = v;
        }
    if (n32 == 0) {
#pragma unroll
        for (int s = 0; s < 2; ++s)
#pragma unroll
            for (int r = 0; r < 16; ++r) {
                int row = (r & 3) + 8 * (r >> 2) + 4 * half;
                int m = mbase + s * 32 + row;
                float dd = fmaxf(qsq[m] - 2.0f * tmax[s][r], 0.f);
                atomicMin(mind2 + m, __float_as_uint(dd));
            }
    }
}

// finalize: out[b] = max_p sqrt(mind2[b*64+p])
__global__ void finalize_kernel(const unsigned int* __restrict__ mind2,
                                float* __restrict__ out) {
    int b = blockIdx.x, l = threadIdx.x;
    float v = __uint_as_float(mind2[b * 64 + l]);
    float d = sqrtf(fmaxf(v, 0.f));
#pragma unroll
    for (int o = 1; o < 64; o <<= 1) d = fmaxf(d, __shfl_xor(d, o, 64));
    if (l == 0) out[b] = d;
}

// ---------------------------------------------------------------------------
extern "C" void kernel_launch(void* const* d_in, const int* in_sizes, int n_in,
                              void* d_out, int out_size, void* d_ws, size_t ws_size,
                              hipStream_t stream) {
    (void)in_sizes; (void)n_in; (void)out_size; (void)ws_size;
    const float* x     = (const float*)d_in[0];
    const float* mbank = (const float*)d_in[1];
    const float* w0 = (const float*)d_in[2],  *b0 = (const float*)d_in[3];
    const float* g0 = (const float*)d_in[4],  *be0 = (const float*)d_in[5];
    const float* mn0 = (const float*)d_in[6], *vr0 = (const float*)d_in[7];
    const float* w1 = (const float*)d_in[8],  *b1 = (const float*)d_in[9];
    const float* g1 = (const float*)d_in[10], *be1 = (const float*)d_in[11];
    const float* mn1 = (const float*)d_in[12], *vr1 = (const float*)d_in[13];
    const float* w2 = (const float*)d_in[14], *b2 = (const float*)d_in[15];
    const float* g2 = (const float*)d_in[16], *be2 = (const float*)d_in[17];
    const float* mn2 = (const float*)d_in[18], *vr2 = (const float*)d_in[19];

    char* ws = (char*)d_ws;
    float*        y0    = (float*)(ws + 0);              // 16.78 MB
    float*        y1    = (float*)(ws + 16777216);       // 8.39 MB
    float*        y2    = (float*)(ws + 25165824);       // 4.19 MB
    __bf16*       qbf   = (__bf16*)(ws + 29360128);      // 2.10 MB
    float*        qsq   = (float*)(ws + 31457280);       // 64 KB
    __bf16*       mbbf  = (__bf16*)(ws + 31522816);      // 33.55 MB
    float*        msq   = (float*)(ws + 65077248);       // 1.05 MB
    unsigned int* mind2 = (unsigned int*)(ws + 66125824);// 64 KB

    conv0_kernel<<<16384, 256, 0, stream>>>(x, w0, b0, g0, be0, mn0, vr0, y0);
    conv1_kernel<<<1024, 256, 0, stream>>>(y0, w1, b1, g1, be1, mn1, vr1, y1);
    conv2_kernel<<<1024, 256, 0, stream>>>(y1, w2, b2, g2, be2, mn2, vr2, y2);
    qnorm_kernel<<<256, 64, 0, stream>>>(y2, qbf, qsq);
    mbnorm_kernel<<<65536, 256, 0, stream>>>(mbank, mbbf, msq);
    initmin_kernel<<<64, 256, 0, stream>>>(mind2);
    dist_kernel<<<dim3(64, SLICES), 256, 0, stream>>>(qbf, qsq, mbbf, msq, mind2);
    finalize_kernel<<<256, 64, 0, stream>>>(mind2, (float*)d_out);
}